// Round 8
// baseline (30.049 us; speedup 1.0000x reference)
//
#include <hip/hip_runtime.h>

// ConvTranspose3d-via-FFT == circular 3^3 conv on 2x-upsampled grid.
// Parity decomposition (verified): out[b,i,2q+p] = sum_{j,t} We_p[i][j][t] * x[b,j,(q-t) mod 16]
//   p=0: t0 <- k0,    t1 <- k1+k2
//   p=1: t0 <- k0+k1, t1 <- k2     (per axis, circular mod 16)
//
// Round 8: clean occupancy experiment with A kept in LDS. Split pw across
// blocks: 1024 blocks x 256 threads, 32KB LDS (one pw panel) -> 4-5 blk/CU
// = 4-5 waves/SIMD (vs 2 in R4/R5 which timed identically). Wave = batch,
// acc = one f32x16, low VGPR for deep load pipelining.

typedef float f32x16 __attribute__((ext_vector_type(16)));
typedef short s16x8 __attribute__((ext_vector_type(8)));

#define CI  64
#define CO  32
#define QV  4096                     // 16^3
#define XT_ELEMS (4 * QV * CI)       // 1048576 bf16
// WeG layout: [pp=4][plane=16][chunk=8][i=32][e=8] bf16 ; plane = pw*8 + t
#define WE_ELEMS (4 * 16 * 8 * 32 * 8)
#define WE_PP    (16 * 8 * 32 * 8)   // 32768 elems per (pd,ph)
#define WE_HALF  (8 * 8 * 32 * 8)    // 16384 elems per pw-half (32 KB)

__device__ __forceinline__ unsigned short f32_to_bf16_rne(float f) {
    union { float f; unsigned u; } v; v.f = f;
    unsigned u = v.u;
    unsigned r = u + 0x7FFFu + ((u >> 16) & 1u);
    return (unsigned short)(r >> 16);
}

// ---- fused prep: blocks [0,512) transpose x -> xT[b][q][j] bf16;
//      blocks [512,576) build WeG ----
__global__ __launch_bounds__(256)
void prep_kernel(const float* __restrict__ x, const float* __restrict__ weight,
                 unsigned short* __restrict__ xT, unsigned short* __restrict__ WeG) {
    const int blk = blockIdx.x;
    if (blk < 512) {
        const int tid = blk * 256 + threadIdx.x;        // 131072: (b, jj, q)
        const int b  = tid >> 15;
        const int rem = tid & 32767;
        const int jj = rem >> 12;                        // 8 chunks of 8 j
        const int q  = rem & 4095;                       // lane-consecutive
        const float* xb = x + b * (CI * QV) + q;
        s16x8 pk;
        #pragma unroll
        for (int e = 0; e < 8; ++e)
            pk[e] = (short)f32_to_bf16_rne(xb[(jj * 8 + e) * QV]);
        *reinterpret_cast<s16x8*>(xT + ((size_t)(b * QV + q)) * CI + jj * 8) = pk;
    } else {
        const int tid = (blk - 512) * 256 + threadIdx.x; // 16384: p*2048+i*64+j
        const int p = tid >> 11, i = (tid >> 6) & 31, j = tid & 63;
        const int pd = p >> 2, ph = (p >> 1) & 1, pw = p & 1;
        const int pp = pd * 2 + ph;

        const float* wp = weight + (i * CI + j) * 27;
        float wv[27];
        #pragma unroll
        for (int k = 0; k < 27; ++k) wv[k] = wp[k];

        float t1[2][9];
        #pragma unroll
        for (int m = 0; m < 9; ++m) {
            t1[0][m] = pd ? (wv[m] + wv[9 + m]) : wv[m];
            t1[1][m] = pd ? wv[18 + m] : (wv[9 + m] + wv[18 + m]);
        }
        float t2[2][2][3];
        #pragma unroll
        for (int td = 0; td < 2; ++td)
            #pragma unroll
            for (int m = 0; m < 3; ++m) {
                t2[td][0][m] = ph ? (t1[td][m] + t1[td][3 + m]) : t1[td][m];
                t2[td][1][m] = ph ? t1[td][6 + m] : (t1[td][3 + m] + t1[td][6 + m]);
            }

        const int c = j >> 3, e = j & 7;   // k-chunk, element
        #pragma unroll
        for (int td = 0; td < 2; ++td)
            #pragma unroll
            for (int th = 0; th < 2; ++th) {
                float a0 = pw ? (t2[td][th][0] + t2[td][th][1]) : t2[td][th][0];
                float a1 = pw ? t2[td][th][2] : (t2[td][th][1] + t2[td][th][2]);
                const int tA = td * 4 + th * 2;          // tw=0
                const int plane0 = pw * 8 + tA;
                WeG[(((pp * 16 + plane0) * 8 + c) * 32 + i) * 8 + e]     = f32_to_bf16_rne(a0);
                WeG[(((pp * 16 + plane0 + 1) * 8 + c) * 32 + i) * 8 + e] = f32_to_bf16_rne(a1);
            }
    }
}

// ---- main: 1024 blocks x 256 threads; block = (pd,ph,pw) x 1 q-tile,
//      4 waves = 4 batches; 32KB LDS pw-panel; 4-5 blocks/CU ----
__global__ __launch_bounds__(256, 4)
void convt3d_mfma_kernel(const unsigned short* __restrict__ xT,
                         const unsigned short* __restrict__ WeG,
                         float* __restrict__ out) {
    __shared__ unsigned short we_lds[WE_HALF];   // 32 KB

    const int blk = blockIdx.x;          // 1024
    const int ppw = blk >> 7;            // (pd,ph,pw)
    const int T   = blk & 127;           // q-tile
    const int pp  = ppw >> 1, pw = ppw & 1;
    const int pd  = pp >> 1,  ph = pp & 1;

    // stage the 32KB pw-panel: 8 passes of 256 threads x 16B
    {
        const char* src = (const char*)(WeG + pp * WE_PP + pw * WE_HALF);
        char* dst = (char*)we_lds;
        #pragma unroll
        for (int pass = 0; pass < 8; ++pass) {
            const int off = pass * 4096 + threadIdx.x * 16;
            *reinterpret_cast<s16x8*>(dst + off) =
                *reinterpret_cast<const s16x8*>(src + off);
        }
    }
    __syncthreads();

    const int b    = threadIdx.x >> 6;   // wave = batch
    const int l    = threadIdx.x & 63;
    const int n    = l & 31;             // output column
    const int half = l >> 5;             // k-group

    const int qd = T >> 3;
    const int qh = (T & 7) * 2 + (n >> 4);
    const int qw = n & 15;

    f32x16 acc = {};
    const unsigned short* xTb = xT + (size_t)b * (QV * CI);

    #pragma unroll
    for (int t = 0; t < 8; ++t) {
        const int td = t >> 2, th = (t >> 1) & 1, tw = t & 1;
        const int dd = (qd - td) & 15, hh = (qh - th) & 15, ww = (qw - tw) & 15;
        const unsigned short* brow = xTb + ((dd * 16 + hh) * 16 + ww) * CI + half * 8;
        #pragma unroll
        for (int ks = 0; ks < 4; ++ks) {
            const int c = 2 * ks + half;             // j-chunk
            const s16x8 bfrag = *reinterpret_cast<const s16x8*>(brow + ks * 16);
            const s16x8 a = *reinterpret_cast<const s16x8*>(
                we_lds + ((t * 8 + c) * 32 + n) * 8);
            acc = __builtin_amdgcn_mfma_f32_32x32x16_bf16(a, bfrag, acc, 0, 0, 0);
        }
    }

    // D layout: col n = l&31, row m = (r&3) + 8*(r>>2) + 4*half
    const int d = 2 * qd + pd, h = 2 * qh + ph, w = 2 * qw + pw;
    float* ob = out + ((size_t)b * CO) * 32768 + d * 1024 + h * 32 + w;
    #pragma unroll
    for (int r = 0; r < 16; ++r) {
        const int m = (r & 3) + 8 * (r >> 2) + 4 * half;
        ob[(size_t)m * 32768] = acc[r];
    }
}

extern "C" void kernel_launch(void* const* d_in, const int* in_sizes, int n_in,
                              void* d_out, int out_size, void* d_ws, size_t ws_size,
                              hipStream_t stream) {
    const float* x      = (const float*)d_in[0];
    const float* weight = (const float*)d_in[1];
    float* out          = (float*)d_out;

    unsigned short* xT = (unsigned short*)d_ws;
    unsigned short* We = xT + XT_ELEMS;

    prep_kernel<<<576, 256, 0, stream>>>(x, weight, xT, We);
    convt3d_mfma_kernel<<<1024, 256, 0, stream>>>(xT, We, out);
}

// Round 9
// 18.171 us; speedup vs baseline: 1.6537x; 1.6537x over previous
//
#include <hip/hip_runtime.h>

// ConvTranspose3d-via-FFT == circular 3^3 conv on 2x-upsampled grid.
// Parity decomposition (verified): out[b,i,2q+p] = sum_{j,t} We_p[i][j][t] * x[b,j,(q-t) mod 16]
//   p=0: t0 <- k0,    t1 <- k1+k2
//   p=1: t0 <- k0+k1, t1 <- k2     (per axis, circular mod 16)
//
// Round 9: B-path coalescing. xT re-laid as [b][c=j>>3][q][e=j&7] so a
// B-fragment load (lanes = consecutive q, fixed chunk) reads contiguous 16B
// chunks (512B/half-wave segment) instead of 16B-every-128B. Main kernel
// otherwise identical to R5 (best). We-build folded into transpose blocks.

typedef float f32x16 __attribute__((ext_vector_type(16)));
typedef short s16x8 __attribute__((ext_vector_type(8)));

#define CI  64
#define CO  32
#define QV  4096                     // 16^3
#define XT_ELEMS (4 * QV * CI)       // 1048576 bf16
// WeG layout: [pp=4][plane=16][chunk=8][i=32][e=8] bf16 ; plane = pw*8 + t
#define WE_ELEMS (4 * 16 * 8 * 32 * 8)
#define WE_PP    (16 * 8 * 32 * 8)   // 32768 elems per (pd,ph)

__device__ __forceinline__ unsigned short f32_to_bf16_rne(float f) {
    union { float f; unsigned u; } v; v.f = f;
    unsigned u = v.u;
    unsigned r = u + 0x7FFFu + ((u >> 16) & 1u);
    return (unsigned short)(r >> 16);
}

// ---- prep: 512 blocks. All threads: transpose x -> xT2[b][c][q][e] bf16.
//      Lanes 0-31 additionally build one WeG item each (512*32 = 16384). ----
__global__ __launch_bounds__(256)
void prep_kernel(const float* __restrict__ x, const float* __restrict__ weight,
                 unsigned short* __restrict__ xT, unsigned short* __restrict__ WeG) {
    const int blk = blockIdx.x;
    {
        const int tid = blk * 256 + threadIdx.x;        // 131072: (b, c, q)
        const int b  = tid >> 15;
        const int rem = tid & 32767;
        const int c  = rem >> 12;                        // j-chunk
        const int q  = rem & 4095;                       // lane-consecutive
        const float* xb = x + b * (CI * QV) + q;
        s16x8 pk;
        #pragma unroll
        for (int e = 0; e < 8; ++e)
            pk[e] = (short)f32_to_bf16_rne(xb[(c * 8 + e) * QV]);
        // xT2 idx: ((b*8 + c)*4096 + q)*8  -> lanes write consecutive 16B
        *reinterpret_cast<s16x8*>(xT + (((size_t)(b * 8 + c)) * QV + q) * 8) = pk;
    }
    if (threadIdx.x < 32) {
        const int tid = blk * 32 + threadIdx.x;          // 16384: p*2048+i*64+j
        const int p = tid >> 11, i = (tid >> 6) & 31, j = tid & 63;
        const int pd = p >> 2, ph = (p >> 1) & 1, pw = p & 1;
        const int pp = pd * 2 + ph;

        const float* wp = weight + (i * CI + j) * 27;
        float wv[27];
        #pragma unroll
        for (int k = 0; k < 27; ++k) wv[k] = wp[k];

        float t1[2][9];
        #pragma unroll
        for (int m = 0; m < 9; ++m) {
            t1[0][m] = pd ? (wv[m] + wv[9 + m]) : wv[m];
            t1[1][m] = pd ? wv[18 + m] : (wv[9 + m] + wv[18 + m]);
        }
        float t2[2][2][3];
        #pragma unroll
        for (int td = 0; td < 2; ++td)
            #pragma unroll
            for (int m = 0; m < 3; ++m) {
                t2[td][0][m] = ph ? (t1[td][m] + t1[td][3 + m]) : t1[td][m];
                t2[td][1][m] = ph ? (t1[td][6 + m]) : (t1[td][3 + m] + t1[td][6 + m]);
            }

        const int c = j >> 3, e = j & 7;   // k-chunk, element
        #pragma unroll
        for (int td = 0; td < 2; ++td)
            #pragma unroll
            for (int th = 0; th < 2; ++th) {
                float a0 = pw ? (t2[td][th][0] + t2[td][th][1]) : t2[td][th][0];
                float a1 = pw ? t2[td][th][2] : (t2[td][th][1] + t2[td][th][2]);
                const int tA = td * 4 + th * 2;          // tw=0
                const int plane0 = pw * 8 + tA;
                WeG[(((pp * 16 + plane0) * 8 + c) * 32 + i) * 8 + e]     = f32_to_bf16_rne(a0);
                WeG[(((pp * 16 + plane0 + 1) * 8 + c) * 32 + i) * 8 + e] = f32_to_bf16_rne(a1);
            }
    }
}

// ---- main: 512 blocks x 256 threads; block = (pd,ph) x 1 q-tile, 4 waves =
//      4 batches sharing one 64KB LDS copy of We(pd,ph) ----
__global__ __launch_bounds__(256)
void convt3d_mfma_kernel(const unsigned short* __restrict__ xT,
                         const unsigned short* __restrict__ WeG,
                         float* __restrict__ out) {
    __shared__ unsigned short we_lds[WE_PP];   // 64 KB

    const int blk = blockIdx.x;          // 512
    const int pp  = blk >> 7;            // (pd,ph)
    const int T   = blk & 127;           // q-tile
    const int pd = pp >> 1, ph = pp & 1;

    // stage We(pd,ph): 64KB, 16 passes of 256 threads x 16B (lane-consecutive)
    {
        const char* src = (const char*)(WeG + pp * WE_PP);
        char* dst = (char*)we_lds;
        #pragma unroll
        for (int pass = 0; pass < 16; ++pass) {
            const int off = pass * 4096 + threadIdx.x * 16;
            *reinterpret_cast<s16x8*>(dst + off) =
                *reinterpret_cast<const s16x8*>(src + off);
        }
    }
    __syncthreads();

    const int b    = threadIdx.x >> 6;   // wave = batch
    const int l    = threadIdx.x & 63;
    const int n    = l & 31;             // output column
    const int half = l >> 5;             // k-group

    const int qd = T >> 3;
    const int qh = (T & 7) * 2 + (n >> 4);
    const int qw = n & 15;

    f32x16 acc0 = {};
    f32x16 acc1 = {};
    // xT2 layout: [b][c=8][q=4096][e=8]
    const unsigned short* xTb = xT + (size_t)b * (CI * QV);

    #pragma unroll
    for (int t = 0; t < 8; ++t) {
        const int td = t >> 2, th = (t >> 1) & 1, tw = t & 1;
        const int dd = (qd - td) & 15, hh = (qh - th) & 15, ww = (qw - tw) & 15;
        const int qpos = (dd * 16 + hh) * 16 + ww;
        #pragma unroll
        for (int ks = 0; ks < 4; ++ks) {
            const int c = 2 * ks + half;             // j-chunk
            const s16x8 bfrag = *reinterpret_cast<const s16x8*>(
                xTb + ((size_t)c * QV + qpos) * 8);
            const s16x8 a0 = *reinterpret_cast<const s16x8*>(
                we_lds + ((t * 8 + c) * 32 + n) * 8);
            const s16x8 a1 = *reinterpret_cast<const s16x8*>(
                we_lds + (((8 + t) * 8 + c) * 32 + n) * 8);
            acc0 = __builtin_amdgcn_mfma_f32_32x32x16_bf16(a0, bfrag, acc0, 0, 0, 0);
            acc1 = __builtin_amdgcn_mfma_f32_32x32x16_bf16(a1, bfrag, acc1, 0, 0, 0);
        }
    }

    // D layout: col n = l&31, row m = (r&3) + 8*(r>>2) + 4*half
    const int d = 2 * qd + pd, h = 2 * qh + ph, wq = 2 * qw;
    #pragma unroll
    for (int r = 0; r < 16; ++r) {
        const int m = (r & 3) + 8 * (r >> 2) + 4 * half;
        float2 v; v.x = acc0[r]; v.y = acc1[r];      // pw = 0, 1
        *reinterpret_cast<float2*>(out + (((size_t)b * CO + m) * 32 + d) * 1024 + h * 32 + wq) = v;
    }
}

extern "C" void kernel_launch(void* const* d_in, const int* in_sizes, int n_in,
                              void* d_out, int out_size, void* d_ws, size_t ws_size,
                              hipStream_t stream) {
    const float* x      = (const float*)d_in[0];
    const float* weight = (const float*)d_in[1];
    float* out          = (float*)d_out;

    unsigned short* xT = (unsigned short*)d_ws;
    unsigned short* We = xT + XT_ELEMS;

    prep_kernel<<<512, 256, 0, stream>>>(x, weight, xT, We);
    convt3d_mfma_kernel<<<512, 256, 0, stream>>>(xT, We, out);
}